// Round 12
// baseline (476.911 us; speedup 1.0000x reference)
//
#include <hip/hip_runtime.h>

// FeedBack LSTM: B=1024, T_in=128, F=3, UNITS=256, out_steps=32.
// R12 = R11 (monolithic 32-MFMA block, VGPR=128 residency signature, tid0
// sentinel + bulk tagged load) with the PUBLISH path shortened:
//   - tagged words stored straight from gate registers (4 dwords/lane),
//     per-wave, NO B3 barrier, no LDS->register repack: stores take flight
//     ~0.4us earlier, so the peer's detect usually hits first try.
//   - B3 deleted; next step's B1 (post-bulk-load __syncthreads) provides all
//     LDS ordering (hfull is parity double-buffered; no intra-step WAR).
//   - sentinel poll is one 8B load (words 0,1 = lanes 0,1's FIRST stores).
// Scattered-publish overwrite safety: our word-i overwrite (tag t+2) is
// after our block-wide B1(t+2), which waited on tag t+1 from EVERY peer
// thread; each peer publish is issue-after-return of that thread's bulk
// read of our tag-t words => every reader of word i finished before its
// overwriter fires. Per-thread backstop retry (s_sleep(8)) unchanged.

#define TIN    128
#define FIN    3
#define OSTEPS 32
#define LASTT  (TIN + OSTEPS - 1)   // t = 0..159; t==159 is head-only

typedef float    f32x4 __attribute__((ext_vector_type(4)));
typedef _Float16 half8 __attribute__((ext_vector_type(8)));
typedef unsigned long long u64;
typedef unsigned int u32;

__device__ __forceinline__ float fast_rcp(float x) { return __builtin_amdgcn_rcpf(x); }
__device__ __forceinline__ float sigm(float x)  { return fast_rcp(1.0f + __expf(-x)); }
__device__ __forceinline__ float tanh_f(float x){ return 1.0f - 2.0f * fast_rcp(__expf(2.0f * x) + 1.0f); }

// Pack Wr [256][1024] fp32 -> fp16 B-frags. Tile T = p*32 + q*8 + w covers
// cols q*256 + p*128 + w*16 + (l&15); k = kt*32 + (l>>4)*8 + j.
// P[(T*8+kt)*512 + l*8 + j] = Wr[k][col]
__global__ __launch_bounds__(512) void pack_wr(const float* __restrict__ Wr,
                                               _Float16* __restrict__ P)
{
    int idx = blockIdx.x * 512 + threadIdx.x;   // 64 blocks -> 32768
    int l   = idx & 63;
    int kt  = (idx >> 6) & 7;
    int T   = idx >> 9;                         // 0..63
    int p = T >> 5, q = (T >> 3) & 3, w = T & 7;
    int col = q * 256 + p * 128 + w * 16 + (l & 15);
    int k0  = kt * 32 + (l >> 4) * 8;
    half8 v;
#pragma unroll
    for (int j = 0; j < 8; ++j) v[j] = (_Float16)Wr[(k0 + j) * 1024 + col];
    *reinterpret_cast<half8*>(P + (size_t)idx * 8) = v;
}

__global__ __launch_bounds__(512, 2) void lstm_pair(
    const float* __restrict__ x_in,   // [1024][128][3]
    const float* __restrict__ Wk,     // [3][1024]
    const float* __restrict__ bias,   // [1024]
    const float* __restrict__ Wd,     // [256][3]
    const float* __restrict__ bd,     // [3]
    const _Float16* __restrict__ WrP, // packed B-frags
    u32*   __restrict__ hexT,         // [2 par][64 grp][2 mem][2048] tagged words
    float* __restrict__ out)          // [1024][32][3]
{
    __shared__ float                xs[16 * TIN * FIN];  // 24 KB staged inputs
    __shared__ alignas(16) _Float16 hfull[2][4096];      // full h, A-frag order
    __shared__ float                pred_buf[16][4];     // fed-back prediction

    const int tid  = threadIdx.x;
    const int w    = tid >> 6;            // wave 0..7
    const int l    = tid & 63;
    const int n    = l & 15;
    const int row0 = (l >> 4) * 4;        // MFMA C rows for this lane
    const int bid  = blockIdx.x;
    const int p    = (bid >> 3) & 1;      // member: units [p*128,(p+1)*128)
    const int pp   = 1 - p;
    const int g    = (bid & 7) + 8 * (bid >> 4);   // group 0..63; pair = same XCD

    // ---- prologue ----
    const float* xsrc = x_in + (size_t)g * 16 * TIN * FIN;
    for (int i = tid; i < 16 * TIN * FIN; i += 512) xs[i] = xsrc[i];

    half8 bfr[4][8];                      // weight slice (AGPR/VGPR resident)
#pragma unroll
    for (int q = 0; q < 4; ++q)
#pragma unroll
        for (int kt = 0; kt < 8; ++kt)
            bfr[q][kt] = *reinterpret_cast<const half8*>(
                WrP + (((size_t)(p * 32 + q * 8 + w) * 8 + kt) * 512 + l * 8));

    float b_r[4], wk_r[4][3];
#pragma unroll
    for (int q = 0; q < 4; ++q) {
        int col = q * 256 + p * 128 + w * 16 + n;
        b_r[q] = bias[col];
#pragma unroll
        for (int f = 0; f < 3; ++f) wk_r[q][f] = Wk[f * 1024 + col];
    }
    float wd_r[4][3];                     // head: lane l covers units 4l..4l+3
#pragma unroll
    for (int j = 0; j < 4; ++j)
#pragma unroll
        for (int f = 0; f < 3; ++f) wd_r[j][f] = Wd[(4 * l + j) * 3 + f];
    const float bd0 = bd[0], bd1 = bd[1], bd2 = bd[2];

    float c_st[4] = {0.f, 0.f, 0.f, 0.f};
    const int hloc = (w >> 1) * 512 + ((2 * w + (n >> 3)) & 3) * 128
                   + row0 * 8 + (n & 7);
    const int hpos = p * 2048 + hloc;     // own h position in hfull

    __syncthreads();

    for (int t = 0; t <= LASTT; ++t) {
        const int par_rd = (t - 1) & 1;   // parity holding h_{t-1} (t>0)

        // ---- acquire h_{t-1}: tid0 8B sentinel -> barrier -> bulk load ----
        if (t > 0) {
            const u64* src = reinterpret_cast<const u64*>(
                hexT + (((size_t)par_rd * 64 + g) * 2 + pp) * 2048);
            const u64 msk = 0x0000FFFF0000FFFFull;
            const u64 tg2 = (u64)(u32)(t - 1) * 0x0000000100000001ull;
            if (tid == 0) {               // quiet: one 8B line, one poller
                u64 s0;
                do {
                    s0 = __hip_atomic_load(src, __ATOMIC_RELAXED, __HIP_MEMORY_SCOPE_AGENT);
                } while ((s0 & msk) != tg2);
            }
            __syncthreads();              // B0: peer burst confirmed in flight
            u64 w0 = __hip_atomic_load(src + tid * 2 + 0, __ATOMIC_RELAXED, __HIP_MEMORY_SCOPE_AGENT);
            u64 w1 = __hip_atomic_load(src + tid * 2 + 1, __ATOMIC_RELAXED, __HIP_MEMORY_SCOPE_AGENT);
            while (((w0 & msk) != tg2) || ((w1 & msk) != tg2)) {   // rare backstop
                __builtin_amdgcn_s_sleep(8);
                w0 = __hip_atomic_load(src + tid * 2 + 0, __ATOMIC_RELAXED, __HIP_MEMORY_SCOPE_AGENT);
                w1 = __hip_atomic_load(src + tid * 2 + 1, __ATOMIC_RELAXED, __HIP_MEMORY_SCOPE_AGENT);
            }
            u64 hv = ((w0 >> 16) & 0xFFFFull)
                   | ((w0 >> 48) << 16)
                   | (((w1 >> 16) & 0xFFFFull) << 32)
                   | ((w1 >> 48) << 48);
            reinterpret_cast<u64*>(&hfull[par_rd][pp * 2048])[tid] = hv;
            __syncthreads();              // B1: all LDS ordering for this step
        }

        // ---- head phase (t>=128): pred_s from h_{t-1}, s = t-128 ----
        if (t >= TIN) {
            const int s = t - TIN;
#pragma unroll
            for (int rr = 0; rr < 2; ++rr) {
                int row = 2 * w + rr;     // wave w reduces batch rows 2w, 2w+1
                const _Float16* hb = &hfull[par_rd][(l >> 3) * 512
                                   + ((l >> 1) & 3) * 128 + row * 8 + 4 * (l & 1)];
                float p0 = 0.f, p1 = 0.f, p2 = 0.f;
#pragma unroll
                for (int j = 0; j < 4; ++j) {
                    float hj = (float)hb[j];
                    p0 += hj * wd_r[j][0];
                    p1 += hj * wd_r[j][1];
                    p2 += hj * wd_r[j][2];
                }
#pragma unroll
                for (int o = 32; o > 0; o >>= 1) {
                    p0 += __shfl_xor(p0, o);
                    p1 += __shfl_xor(p1, o);
                    p2 += __shfl_xor(p2, o);
                }
                if (l == 0) {
                    p0 += bd0; p1 += bd1; p2 += bd2;
                    pred_buf[row][0] = p0; pred_buf[row][1] = p1; pred_buf[row][2] = p2;
                    if (p == 0) {
                        float* op = out + ((size_t)(g * 16 + row) * OSTEPS + s) * 3;
                        op[0] = p0; op[1] = p1; op[2] = p2;
                    }
                }
            }
            __syncthreads();              // B2: pred_buf ready
            if (t == LASTT) break;        // s=31 stored; done
        }

        // ---- A-fragments (static indices; zeros at t=0) ----
        half8 a[8];
        if (t > 0) {
#pragma unroll
            for (int kt = 0; kt < 8; ++kt)
                a[kt] = *reinterpret_cast<const half8*>(&hfull[par_rd][kt * 512 + l * 8]);
        } else {
            half8 az = {};
#pragma unroll
            for (int kt = 0; kt < 8; ++kt) a[kt] = az;
        }

        // ---- x for this cell step ----
        float xv[4][3];
#pragma unroll
        for (int r = 0; r < 4; ++r) {
            int row = row0 + r;
            if (t >= TIN) {
                xv[r][0] = pred_buf[row][0];
                xv[r][1] = pred_buf[row][1];
                xv[r][2] = pred_buf[row][2];
            } else {
                const float* xp = &xs[(row * TIN + t) * 3];
                xv[r][0] = xp[0]; xv[r][1] = xp[1]; xv[r][2] = xp[2];
            }
        }

        // ---- z = b + x@Wk + h@Wr (32 MFMA, MONOLITHIC -- keep bfr resident) ----
        f32x4 acc[4];
#pragma unroll
        for (int q = 0; q < 4; ++q)
#pragma unroll
            for (int r = 0; r < 4; ++r)
                acc[q][r] = b_r[q] + xv[r][0] * wk_r[q][0]
                          + xv[r][1] * wk_r[q][1] + xv[r][2] * wk_r[q][2];
#pragma unroll
        for (int kt = 0; kt < 8; ++kt)
#pragma unroll
            for (int q = 0; q < 4; ++q)
                acc[q] = __builtin_amdgcn_mfma_f32_16x16x32_f16(a[kt], bfr[q][kt], acc[q], 0, 0, 0);

        // ---- gates (in-lane), c update; publish STRAIGHT FROM REGISTERS ----
        const int par_wr = t & 1;
        u32* wdst = hexT + (((size_t)par_wr * 64 + g) * 2 + p) * 2048 + hloc;
#pragma unroll
        for (int r = 0; r < 4; ++r) {
            float iv = sigm(acc[0][r]);
            float fv = sigm(acc[1][r]);
            float gv = tanh_f(acc[2][r]);
            float ov = sigm(acc[3][r]);
            float cc = fv * c_st[r] + iv * gv;
            c_st[r] = cc;
            _Float16 hh = (_Float16)(ov * tanh_f(cc));
            u32 tw = ((u32)__builtin_bit_cast(unsigned short, hh) << 16) | (u32)t;
            __hip_atomic_store(wdst + r * 8, tw, __ATOMIC_RELAXED,
                               __HIP_MEMORY_SCOPE_AGENT);        // earliest flight
            hfull[par_wr][hpos + r * 8] = hh;                    // local copy
        }
        // NO B3: next step's B1 orders hfull writes; publish self-validates.
    }
}

extern "C" void kernel_launch(void* const* d_in, const int* in_sizes, int n_in,
                              void* d_out, int out_size, void* d_ws, size_t ws_size,
                              hipStream_t stream)
{
    const float* x  = (const float*)d_in[0];
    const float* Wk = (const float*)d_in[1];
    const float* Wr = (const float*)d_in[2];
    const float* b  = (const float*)d_in[3];
    const float* Wd = (const float*)d_in[4];
    const float* bd = (const float*)d_in[5];
    float* out = (float*)d_out;

    // d_ws: [0,512K) WrP | [512K, 512K+2M) tagged hex
    _Float16* WrP  = (_Float16*)d_ws;
    u32*      hexT = (u32*)((char*)d_ws + 524288);

    hipMemsetAsync(hexT, 0xFF, 2097152, stream);    // tag 0xFFFF: never matches
    pack_wr<<<64, 512, 0, stream>>>(Wr, WrP);
    lstm_pair<<<128, 512, 0, stream>>>(x, Wk, b, Wd, bd, WrP, hexT, out);
}